// Round 9
// baseline (199.759 us; speedup 1.0000x reference)
//
#include <hip/hip_runtime.h>
#include <hip/hip_bf16.h>
#include <math.h>

// OptimizeSNR via MFMA, R9: no-LDS no-barrier streaming.
//   out[n, 16j+m] = sum_p A[m,p] * B[p,n],  A[m,p]=k[p-m] (Toeplitz, VGPRs),
//   B[p,n] = x[row n][16j-PAD+p] loaded DIRECTLY from global (L1/L2 serve the
//   10x overlap between adjacent tiles), converted to bf16 in-reg.
constexpr int Bc = 8, Cc = 128, Lc = 32768, Kc = 129, PAD = Kc / 2;

constexpr int ROWS   = 16;            // channel-rows per block (MFMA N dim)
constexpr int MLEN   = 1024;          // positions per block (4 waves x 16 tiles x 16)
constexpr int THREADS= 256;
constexpr int TPW    = 16;            // tiles per wave

typedef __attribute__((ext_vector_type(8))) short short8;
typedef __attribute__((ext_vector_type(4))) float floatx4;

__device__ __forceinline__ unsigned short f2bf(float f) {
    return __builtin_bit_cast(unsigned short, __float2bfloat16(f));
}

__device__ __forceinline__ short8 cvt8(const float4& a, const float4& b) {
    __hip_bfloat162 p0 = __float22bfloat162_rn(make_float2(a.x, a.y));
    __hip_bfloat162 p1 = __float22bfloat162_rn(make_float2(a.z, a.w));
    __hip_bfloat162 p2 = __float22bfloat162_rn(make_float2(b.x, b.y));
    __hip_bfloat162 p3 = __float22bfloat162_rn(make_float2(b.z, b.w));
    ushort2 u0, u1, u2, u3;
    __builtin_memcpy(&u0, &p0, 4);
    __builtin_memcpy(&u1, &p1, 4);
    __builtin_memcpy(&u2, &p2, 4);
    __builtin_memcpy(&u3, &p3, 4);
    short8 r;
    r[0] = (short)u0.x; r[1] = (short)u0.y;
    r[2] = (short)u1.x; r[3] = (short)u1.y;
    r[4] = (short)u2.x; r[5] = (short)u2.y;
    r[6] = (short)u3.x; r[7] = (short)u3.y;
    return r;
}

// Per-channel complex scale: sc = nm*cos(atan(a)), ss = nm*sin(atan(a))
__global__ void scale_kernel(const float* __restrict__ wm,
                             const float* __restrict__ wa,
                             float* __restrict__ ws, int C, float batchf) {
    int c = threadIdx.x;
    if (c >= C) return;
    float m = -1e30f;
    for (int i = 0; i < C; ++i) m = fmaxf(m, wm[i]);
    float s = 0.f;
    for (int i = 0; i < C; ++i) s += expf(wm[i] - m);
    float nm = batchf * expf(wm[c] - m) / s;
    float a = wa[c];
    float inv = rsqrtf(1.f + a * a);
    ws[2 * c]     = nm * inv;       // sc
    ws[2 * c + 1] = nm * a * inv;   // ss
}

__global__ __launch_bounds__(THREADS, 5)
void mf_kernel(const float* __restrict__ x,
               const float* __restrict__ kr,
               const float* __restrict__ ki,
               const float* __restrict__ sc_ss,
               float* __restrict__ out, int interleaved) {
    const int bx   = blockIdx.x;       // position chunk (1024 positions)
    const int bg   = blockIdx.y;       // row group (16 rows)
    const int row0 = bg * ROWS;
    const int P0   = bx * MLEN;

    const int tid  = threadIdx.x;
    const int lane = tid & 63;
    const int fh   = lane >> 4;        // 0..3
    const int fn   = lane & 15;        // 0..15
    const int wv   = tid >> 6;         // wave 0..3

    // ---- A fragments: A_d[m][kl] = k[32d + kl - m]; lane holds m=fn, kl=8*fh+e ----
    short8 ar[5], ai[5];
    #pragma unroll
    for (int d = 0; d < 5; ++d) {
        #pragma unroll
        for (int e = 0; e < 8; ++e) {
            int idx = 32 * d + 8 * fh + e - fn;
            bool ok = (idx >= 0) && (idx < Kc);
            ar[d][e] = (short)f2bf(ok ? kr[idx] : 0.f);
            ai[d][e] = (short)f2bf(ok ? ki[idx] : 0.f);
        }
    }

    // ---- per-lane channel scale (lane owns channel-row row0+fn) ----
    const int ch = (row0 + fn) & (Cc - 1);
    const float scv = sc_ss[2 * ch];
    const float ssv = sc_ss[2 * ch + 1];

    const float* __restrict__ xrow = x + (size_t)(row0 + fn) * Lc;
    const int j0 = (P0 >> 4) + wv * TPW;          // first tile of this wave
    const float* p = xrow + (16 * j0 - PAD + 8 * fh);  // deref'd only when interior

    #pragma unroll
    for (int jj = 0; jj < TPW; ++jj, p += 16) {
        const int jt = j0 + jj;
        const int sb = 16 * jt - PAD;             // window start (wave-uniform)
        floatx4 cr  = {0.f, 0.f, 0.f, 0.f};
        floatx4 cim = {0.f, 0.f, 0.f, 0.f};

        if (sb >= 0 && sb + 160 <= Lc) {
            // Fast path: 10 loads in flight, then convert + MFMA.
            float4 f[10];
            #pragma unroll
            for (int d = 0; d < 5; ++d) {
                f[2 * d]     = *reinterpret_cast<const float4*>(p + 32 * d);
                f[2 * d + 1] = *reinterpret_cast<const float4*>(p + 32 * d + 4);
            }
            #pragma unroll
            for (int d = 0; d < 5; ++d) {
                short8 b = cvt8(f[2 * d], f[2 * d + 1]);
                cr  = __builtin_amdgcn_mfma_f32_16x16x32_bf16(ar[d], b, cr, 0, 0, 0);
                cim = __builtin_amdgcn_mfma_f32_16x16x32_bf16(ai[d], b, cim, 0, 0, 0);
            }
        } else {
            // Edge path (first/last tiles of each row): element-guarded.
            #pragma unroll
            for (int d = 0; d < 5; ++d) {
                float4 va, vb;
                const int g0 = sb + 32 * d + 8 * fh;
                va.x = (g0 + 0 >= 0 && g0 + 0 < Lc) ? xrow[g0 + 0] : 0.f;
                va.y = (g0 + 1 >= 0 && g0 + 1 < Lc) ? xrow[g0 + 1] : 0.f;
                va.z = (g0 + 2 >= 0 && g0 + 2 < Lc) ? xrow[g0 + 2] : 0.f;
                va.w = (g0 + 3 >= 0 && g0 + 3 < Lc) ? xrow[g0 + 3] : 0.f;
                vb.x = (g0 + 4 >= 0 && g0 + 4 < Lc) ? xrow[g0 + 4] : 0.f;
                vb.y = (g0 + 5 >= 0 && g0 + 5 < Lc) ? xrow[g0 + 5] : 0.f;
                vb.z = (g0 + 6 >= 0 && g0 + 6 < Lc) ? xrow[g0 + 6] : 0.f;
                vb.w = (g0 + 7 >= 0 && g0 + 7 < Lc) ? xrow[g0 + 7] : 0.f;
                short8 b = cvt8(va, vb);
                cr  = __builtin_amdgcn_mfma_f32_16x16x32_bf16(ar[d], b, cr, 0, 0, 0);
                cim = __builtin_amdgcn_mfma_f32_16x16x32_bf16(ai[d], b, cim, 0, 0, 0);
            }
        }

        // D layout: lane holds D[m = 4*fh + r][n = fn]
        const size_t obase = (size_t)(row0 + fn) * Lc + 16 * jt + 4 * fh;
        if (!interleaved) {
            float4 o;
            o.x = scv * cr[0] - ssv * cim[0];
            o.y = scv * cr[1] - ssv * cim[1];
            o.z = scv * cr[2] - ssv * cim[2];
            o.w = scv * cr[3] - ssv * cim[3];
            *reinterpret_cast<float4*>(out + obase) = o;
        } else {
            float2* o2 = reinterpret_cast<float2*>(out) + obase;
            #pragma unroll
            for (int r = 0; r < 4; ++r) {
                o2[r] = make_float2(scv * cr[r] - ssv * cim[r],
                                    -scv * cim[r] - ssv * cr[r]);
            }
        }
    }
}

extern "C" void kernel_launch(void* const* d_in, const int* in_sizes, int n_in,
                              void* d_out, int out_size, void* d_ws, size_t ws_size,
                              hipStream_t stream) {
    const float* x  = (const float*)d_in[0];
    const float* wm = (const float*)d_in[1];
    const float* wa = (const float*)d_in[2];
    const float* kr = (const float*)d_in[3];
    const float* ki = (const float*)d_in[4];
    float* out = (float*)d_out;
    float* ws  = (float*)d_ws;

    const int C = in_sizes[1];  // 128
    const long long N = (long long)Bc * Cc * Lc;
    const int interleaved = (out_size == 2 * N) ? 1 : 0;

    hipLaunchKernelGGL(scale_kernel, dim3(1), dim3(C), 0, stream,
                       wm, wa, ws, C, (float)Bc);

    dim3 grid(Lc / MLEN, (Bc * Cc) / ROWS);   // 32 x 64 = 2048 blocks
    hipLaunchKernelGGL(mf_kernel, grid, dim3(THREADS), 0, stream,
                       x, kr, ki, ws, out, interleaved);
}

// Round 10
// 132.053 us; speedup vs baseline: 1.5127x; 1.5127x over previous
//
#include <hip/hip_runtime.h>
#include <hip/hip_bf16.h>
#include <math.h>

// OptimizeSNR R10: register-resident sliding-window MFMA. No LDS, no barriers.
// Per wave: 16 rows x SPAN positions. Window = 5 chunks of 32 floats (bf16 in
// VGPRs). Per 32-position pair: load 1 new chunk, 20 MFMAs (tile0 via A,
// tile1 via A' = A shifted 16 taps), 2 stores, shift window.
constexpr int Bc = 8, Cc = 128, Lc = 32768, Kc = 129, PAD = Kc / 2;

constexpr int ROWS  = 16;             // channel-rows per wave (MFMA N dim)
constexpr int SPAN  = 512;            // positions per wave
constexpr int PAIRS = SPAN / 32;      // 16
constexpr int WPB   = 4;              // waves per block
constexpr int MLEN  = SPAN * WPB;     // 2048 positions per block
constexpr int THREADS = 64 * WPB;     // 256

typedef __attribute__((ext_vector_type(8))) short short8;
typedef __attribute__((ext_vector_type(4))) float floatx4;

__device__ __forceinline__ unsigned short f2bf(float f) {
    return __builtin_bit_cast(unsigned short, __float2bfloat16(f));
}

__device__ __forceinline__ short8 cvt8(const float4& a, const float4& b) {
    __hip_bfloat162 p0 = __float22bfloat162_rn(make_float2(a.x, a.y));
    __hip_bfloat162 p1 = __float22bfloat162_rn(make_float2(a.z, a.w));
    __hip_bfloat162 p2 = __float22bfloat162_rn(make_float2(b.x, b.y));
    __hip_bfloat162 p3 = __float22bfloat162_rn(make_float2(b.z, b.w));
    ushort2 u0, u1, u2, u3;
    __builtin_memcpy(&u0, &p0, 4);
    __builtin_memcpy(&u1, &p1, 4);
    __builtin_memcpy(&u2, &p2, 4);
    __builtin_memcpy(&u3, &p3, 4);
    short8 r;
    r[0] = (short)u0.x; r[1] = (short)u0.y;
    r[2] = (short)u1.x; r[3] = (short)u1.y;
    r[4] = (short)u2.x; r[5] = (short)u2.y;
    r[6] = (short)u3.x; r[7] = (short)u3.y;
    return r;
}

// Per-channel complex scale: sc = nm*cos(atan(a)), ss = nm*sin(atan(a))
__global__ void scale_kernel(const float* __restrict__ wm,
                             const float* __restrict__ wa,
                             float* __restrict__ ws, int C, float batchf) {
    int c = threadIdx.x;
    if (c >= C) return;
    float m = -1e30f;
    for (int i = 0; i < C; ++i) m = fmaxf(m, wm[i]);
    float s = 0.f;
    for (int i = 0; i < C; ++i) s += expf(wm[i] - m);
    float nm = batchf * expf(wm[c] - m) / s;
    float a = wa[c];
    float inv = rsqrtf(1.f + a * a);
    ws[2 * c]     = nm * inv;       // sc
    ws[2 * c + 1] = nm * a * inv;   // ss
}

__global__ __launch_bounds__(THREADS, 3)
void mf_kernel(const float* __restrict__ x,
               const float* __restrict__ kr,
               const float* __restrict__ ki,
               const float* __restrict__ sc_ss,
               float* __restrict__ out, int interleaved) {
    const int bx   = blockIdx.x;
    const int bg   = blockIdx.y;
    const int row0 = bg * ROWS;

    const int tid  = threadIdx.x;
    const int lane = tid & 63;
    const int fh   = lane >> 4;        // 0..3
    const int fn   = lane & 15;        // 0..15
    const int wv   = tid >> 6;         // wave 0..3

    const int S = bx * MLEN + wv * SPAN;   // this wave's span start

    // ---- A fragments. A_d[m][kl] = k[32d+kl-m]; A'_d[m][kl] = k[32d+kl-16-m].
    // Lane holds m=fn, kl=8*fh+e.
    short8 ar[5], ai[5], arp[5], aip[5];
    #pragma unroll
    for (int d = 0; d < 5; ++d) {
        #pragma unroll
        for (int e = 0; e < 8; ++e) {
            const int kl  = 8 * fh + e;
            const int idx = 32 * d + kl - fn;
            const int idp = idx - 16;
            bool ok  = (idx >= 0) && (idx < Kc);
            bool okp = (idp >= 0) && (idp < Kc);
            ar[d][e]  = (short)f2bf(ok  ? kr[idx] : 0.f);
            ai[d][e]  = (short)f2bf(ok  ? ki[idx] : 0.f);
            arp[d][e] = (short)f2bf(okp ? kr[idp] : 0.f);
            aip[d][e] = (short)f2bf(okp ? ki[idp] : 0.f);
        }
    }

    // ---- per-lane channel scale (lane owns channel-row row0+fn) ----
    const int ch = (row0 + fn) & (Cc - 1);
    const float scv = sc_ss[2 * ch];
    const float ssv = sc_ss[2 * ch + 1];

    const float* __restrict__ xrow = x + (size_t)(row0 + fn) * Lc;
    float* __restrict__ orow = out + (size_t)(row0 + fn) * Lc;

    // interior: every load this wave issues is in [0, Lc)
    const bool interior = (S - 64 >= 0) && (S + 576 <= Lc);

    // ---- preload window chunks 0..4 (positions S-64 .. S+96) ----
    short8 w[5];
    if (interior) {
        #pragma unroll
        for (int c = 0; c < 5; ++c) {
            const float* p = xrow + (S - 64 + 32 * c + 8 * fh);
            float4 a = *reinterpret_cast<const float4*>(p);
            float4 b = *reinterpret_cast<const float4*>(p + 4);
            w[c] = cvt8(a, b);
        }
    } else {
        #pragma unroll
        for (int c = 0; c < 5; ++c) {
            const int g0 = S - 64 + 32 * c + 8 * fh;
            float4 a, b;
            a.x = (g0 + 0 >= 0 && g0 + 0 < Lc) ? xrow[g0 + 0] : 0.f;
            a.y = (g0 + 1 >= 0 && g0 + 1 < Lc) ? xrow[g0 + 1] : 0.f;
            a.z = (g0 + 2 >= 0 && g0 + 2 < Lc) ? xrow[g0 + 2] : 0.f;
            a.w = (g0 + 3 >= 0 && g0 + 3 < Lc) ? xrow[g0 + 3] : 0.f;
            b.x = (g0 + 4 >= 0 && g0 + 4 < Lc) ? xrow[g0 + 4] : 0.f;
            b.y = (g0 + 5 >= 0 && g0 + 5 < Lc) ? xrow[g0 + 5] : 0.f;
            b.z = (g0 + 6 >= 0 && g0 + 6 < Lc) ? xrow[g0 + 6] : 0.f;
            b.w = (g0 + 7 >= 0 && g0 + 7 < Lc) ? xrow[g0 + 7] : 0.f;
            w[c] = cvt8(a, b);
        }
    }

    #pragma unroll
    for (int i = 0; i < PAIRS; ++i) {
        const int q = S + 32 * i;          // pair covers positions q .. q+31

        // prefetch next chunk (positions q+96 .. q+127) — dead on last iter
        float4 pa, pb;
        if (i < PAIRS - 1) {
            const int g0 = q + 96 + 8 * fh;
            if (interior) {
                pa = *reinterpret_cast<const float4*>(xrow + g0);
                pb = *reinterpret_cast<const float4*>(xrow + g0 + 4);
            } else {
                pa.x = (g0 + 0 < Lc && g0 + 0 >= 0) ? xrow[g0 + 0] : 0.f;
                pa.y = (g0 + 1 < Lc && g0 + 1 >= 0) ? xrow[g0 + 1] : 0.f;
                pa.z = (g0 + 2 < Lc && g0 + 2 >= 0) ? xrow[g0 + 2] : 0.f;
                pa.w = (g0 + 3 < Lc && g0 + 3 >= 0) ? xrow[g0 + 3] : 0.f;
                pb.x = (g0 + 4 < Lc && g0 + 4 >= 0) ? xrow[g0 + 4] : 0.f;
                pb.y = (g0 + 5 < Lc && g0 + 5 >= 0) ? xrow[g0 + 5] : 0.f;
                pb.z = (g0 + 6 < Lc && g0 + 6 >= 0) ? xrow[g0 + 6] : 0.f;
                pb.w = (g0 + 7 < Lc && g0 + 7 >= 0) ? xrow[g0 + 7] : 0.f;
            }
        }

        floatx4 c0r = {0.f, 0.f, 0.f, 0.f}, c0i = {0.f, 0.f, 0.f, 0.f};
        floatx4 c1r = {0.f, 0.f, 0.f, 0.f}, c1i = {0.f, 0.f, 0.f, 0.f};
        #pragma unroll
        for (int d = 0; d < 5; ++d) {
            c0r = __builtin_amdgcn_mfma_f32_16x16x32_bf16(ar[d],  w[d], c0r, 0, 0, 0);
            c0i = __builtin_amdgcn_mfma_f32_16x16x32_bf16(ai[d],  w[d], c0i, 0, 0, 0);
            c1r = __builtin_amdgcn_mfma_f32_16x16x32_bf16(arp[d], w[d], c1r, 0, 0, 0);
            c1i = __builtin_amdgcn_mfma_f32_16x16x32_bf16(aip[d], w[d], c1i, 0, 0, 0);
        }

        // D layout: lane holds D[m = 4*fh + r][n = fn]; tile0 at q, tile1 at q+16
        if (!interleaved) {
            float4 o0, o1;
            o0.x = scv * c0r[0] - ssv * c0i[0];
            o0.y = scv * c0r[1] - ssv * c0i[1];
            o0.z = scv * c0r[2] - ssv * c0i[2];
            o0.w = scv * c0r[3] - ssv * c0i[3];
            o1.x = scv * c1r[0] - ssv * c1i[0];
            o1.y = scv * c1r[1] - ssv * c1i[1];
            o1.z = scv * c1r[2] - ssv * c1i[2];
            o1.w = scv * c1r[3] - ssv * c1i[3];
            *reinterpret_cast<float4*>(orow + q + 4 * fh)      = o0;
            *reinterpret_cast<float4*>(orow + q + 16 + 4 * fh) = o1;
        } else {
            float2* oa = reinterpret_cast<float2*>(out) + ((size_t)(row0 + fn) * Lc + q + 4 * fh);
            float2* ob = oa + 16;
            #pragma unroll
            for (int r = 0; r < 4; ++r) {
                oa[r] = make_float2(scv * c0r[r] - ssv * c0i[r],
                                    -scv * c0i[r] - ssv * c0r[r]);
                ob[r] = make_float2(scv * c1r[r] - ssv * c1i[r],
                                    -scv * c1i[r] - ssv * c1r[r]);
            }
        }

        // shift window; append prefetched chunk
        #pragma unroll
        for (int c = 0; c < 4; ++c) w[c] = w[c + 1];
        if (i < PAIRS - 1) w[4] = cvt8(pa, pb);
    }
}

extern "C" void kernel_launch(void* const* d_in, const int* in_sizes, int n_in,
                              void* d_out, int out_size, void* d_ws, size_t ws_size,
                              hipStream_t stream) {
    const float* x  = (const float*)d_in[0];
    const float* wm = (const float*)d_in[1];
    const float* wa = (const float*)d_in[2];
    const float* kr = (const float*)d_in[3];
    const float* ki = (const float*)d_in[4];
    float* out = (float*)d_out;
    float* ws  = (float*)d_ws;

    const int C = in_sizes[1];  // 128
    const long long N = (long long)Bc * Cc * Lc;
    const int interleaved = (out_size == 2 * N) ? 1 : 0;

    hipLaunchKernelGGL(scale_kernel, dim3(1), dim3(C), 0, stream,
                       wm, wa, ws, C, (float)Bc);

    dim3 grid(Lc / MLEN, (Bc * Cc) / ROWS);   // 16 x 64 = 1024 blocks
    hipLaunchKernelGGL(mf_kernel, grid, dim3(THREADS), 0, stream,
                       x, kr, ki, ws, out, interleaved);
}